// Round 3
// baseline (623.787 us; speedup 1.0000x reference)
//
#include <hip/hip_runtime.h>

#define B_  4
#define S_  2048
#define NX_ 1024
#define H_  16
#define D_  64
#define P_  512
#define NS_ 2560   // P + S
#define BHND_ ((size_t)B_*H_*NS_*D_)   // 10,485,760

typedef __attribute__((ext_vector_type(8))) short bf16x8;
typedef __attribute__((ext_vector_type(4))) float f32x4;
typedef __attribute__((ext_vector_type(4))) float float4v;
typedef __attribute__((ext_vector_type(4))) unsigned short ushort4v;

__device__ __forceinline__ unsigned short f2bf(float f){
  union { float f; unsigned u; } v; v.f = f;
  unsigned r = v.u + 0x7FFFu + ((v.u >> 16) & 1u);
  return (unsigned short)(r >> 16);
}

__device__ __forceinline__ void gll16(const void* g, void* l){
  __builtin_amdgcn_global_load_lds(
      (const __attribute__((address_space(1))) unsigned int*)g,
      (__attribute__((address_space(3))) unsigned int*)l, 16, 0, 0);
}

// ---------------------------------------------------------------- prep kernels

__global__ void cvt_f32_bf16(const float* __restrict__ in, unsigned short* __restrict__ out, int n4){
  for (int i = blockIdx.x*blockDim.x + threadIdx.x; i < n4; i += gridDim.x*blockDim.x){
    float4v v = ((const float4v*)in)[i];
    ushort4v u = { f2bf(v.x), f2bf(v.y), f2bf(v.z), f2bf(v.w) };
    ((ushort4v*)out)[i] = u;
  }
}

// out[n][k] = bf16(in[k][n]); in: [K][N] f32
__global__ void transpose_cvt(const float* __restrict__ in, unsigned short* __restrict__ out, int K, int N){
  __shared__ float tile[32][33];
  int n0 = blockIdx.x*32, k0 = blockIdx.y*32;
  int tx = threadIdx.x & 31, ty = threadIdx.x >> 5;   // 256 thr = 32x8
  #pragma unroll
  for (int r = 0; r < 32; r += 8)
    tile[ty + r][tx] = in[(size_t)(k0 + ty + r)*N + n0 + tx];
  __syncthreads();
  #pragma unroll
  for (int r = 0; r < 32; r += 8)
    out[(size_t)(n0 + ty + r)*K + k0 + tx] = f2bf(tile[tx][ty + r]);
}

// layer_past [2][B][H][512][64] f32 -> present positions 0..511 (f32 passthrough, exact)
__global__ void past_kernel(const float* __restrict__ past, float* __restrict__ present){
  const int total4 = 2*B_*H_*P_*D_/4;  // 1,048,576 float4s
  for (int i = blockIdx.x*blockDim.x + threadIdx.x; i < total4; i += gridDim.x*blockDim.x){
    int d4  = i & 15;
    int pos = (i >> 4) & 511;
    int h   = (i >> 13) & 15;
    int b   = (i >> 17) & 3;
    int kv  = i >> 19;
    float4v v = ((const float4v*)past)[i];
    size_t off = (((size_t)(b*H_ + h))*NS_ + pos)*D_ + d4*4;
    ((float4v*)present)[((size_t)kv*BHND_ + off) >> 2] = v;
  }
}

// ---------------------------------------------------------------- GEMM (m97-style 128x128, BK=32)
// A [M][K] bf16 row-major, Bt [N][K] bf16 (pre-transposed weights), f32 accum.
// EPI 0: qkv epilogue (Q -> bf16 Qb; K/V -> f32 present). EPI 1: f32 out + bias.
template<int EPI>
__global__ __launch_bounds__(256, 2) void gemm_bf16(
    const unsigned short* __restrict__ A,
    const unsigned short* __restrict__ Bt,
    const float* __restrict__ bias,
    const int K, const int N,
    float* __restrict__ out_f32,
    unsigned short* __restrict__ out_q,
    float* __restrict__ present)
{
  __shared__ unsigned short As[128*32];  // 8 KB, [m][k] linear, 64B rows
  __shared__ unsigned short Bs[128*32];
  const int bm = blockIdx.x, bn = blockIdx.y;
  const int tid = threadIdx.x, lane = tid & 63, w = tid >> 6;
  const int wr = w >> 1, wc = w & 1;
  const int g = lane >> 4, li = lane & 15;
  f32x4 acc[4][4] = {};
  const char* Ab = (const char*)A + (size_t)(bm*128)*(K*2);
  const char* Bb = (const char*)Bt + (size_t)(bn*128)*(K*2);

  for (int kt = 0; kt < K; kt += 32){
    #pragma unroll
    for (int c = 0; c < 2; ++c){
      int off = c*4096 + w*1024 + lane*16;  // linear byte offset in 8KB tile
      int row = off >> 6, col = off & 63;
      gll16(Ab + (size_t)row*(K*2) + (size_t)kt*2 + col, (char*)As + c*4096 + w*1024);
      gll16(Bb + (size_t)row*(K*2) + (size_t)kt*2 + col, (char*)Bs + c*4096 + w*1024);
    }
    __syncthreads();
    bf16x8 af[4], bfr[4];
    #pragma unroll
    for (int mf = 0; mf < 4; ++mf)
      af[mf] = *(const bf16x8*)((const char*)As + (wr*64 + mf*16 + li)*64 + g*16);
    #pragma unroll
    for (int nf = 0; nf < 4; ++nf)
      bfr[nf] = *(const bf16x8*)((const char*)Bs + (wc*64 + nf*16 + li)*64 + g*16);
    #pragma unroll
    for (int mf = 0; mf < 4; ++mf)
      #pragma unroll
      for (int nf = 0; nf < 4; ++nf)
        acc[mf][nf] = __builtin_amdgcn_mfma_f32_16x16x32_bf16(af[mf], bfr[nf], acc[mf][nf], 0, 0, 0);
    __syncthreads();
  }

  #pragma unroll
  for (int mf = 0; mf < 4; ++mf){
    #pragma unroll
    for (int nf = 0; nf < 4; ++nf){
      int n = bn*128 + wc*64 + nf*16 + li;
      float bsv = bias[n];
      #pragma unroll
      for (int r = 0; r < 4; ++r){
        int m = bm*128 + wr*64 + mf*16 + g*4 + r;
        float v = acc[mf][nf][r] + bsv;
        if (EPI == 0){
          int b = m >> 11, sI = m & 2047;
          if (n < 1024){
            int hh = n >> 6, d = n & 63;
            out_q[(((size_t)(b*H_ + hh)*S_ + sI) << 6) + d] = f2bf(v);
          } else {
            int cc = n & 1023; int hh = cc >> 6, d = cc & 63;
            size_t off = (((size_t)(b*H_ + hh)*NS_ + P_ + sI) << 6) + d;
            present[(n < 2048 ? (size_t)0 : BHND_) + off] = v;
          }
        } else {
          out_f32[(size_t)m*N + n] = v;
        }
      }
    }
  }
}

// ---------------------------------------------------------------- flash attention
// grid (16 q-blocks, 64 bh); 4 waves x 32 q-rows; KV tile 64.
// K/V read as f32 from present, converted to bf16 during reg-staged LDS writes.
__global__ __launch_bounds__(256, 2) void attn_kernel(
    const unsigned short* __restrict__ Qb,   // [B*H][2048][64] bf16
    const float* __restrict__ presK,         // [B*H][2560][64] f32
    const float* __restrict__ presV,         // [B*H][2560][64] f32
    unsigned short* __restrict__ Aout)       // [B][2048][1024] bf16
{
  __shared__ unsigned short Klds[64*64];     // 8 KB, XOR-swizzled rows (128B)
  __shared__ unsigned short Vt[64*72];       // [d][kv], row stride 144B (16B-aligned)
  __shared__ unsigned short Plds[4][32*72];  // per-wave P tile [q][kv], pad 72

  const int qb = blockIdx.x;
  const int bh = blockIdx.y;
  const int tid = threadIdx.x, lane = tid & 63, w = tid >> 6;
  const int g = lane >> 4, li = lane & 15;
  const int q0 = qb*128 + w*32;

  // Q fragments in registers: rows q0+rf*16+li, k-slices of 8
  bf16x8 qf[2][2];
  #pragma unroll
  for (int rf = 0; rf < 2; ++rf)
    #pragma unroll
    for (int ks = 0; ks < 2; ++ks)
      qf[rf][ks] = *(const bf16x8*)(Qb + (((size_t)bh*S_ + q0 + rf*16 + li) << 6) + ks*32 + g*8);

  f32x4 o[2][4];
  float mrow[2][4], lrow[2][4];
  #pragma unroll
  for (int rf = 0; rf < 2; ++rf){
    #pragma unroll
    for (int df = 0; df < 4; ++df) o[rf][df] = (f32x4){0.f,0.f,0.f,0.f};
    #pragma unroll
    for (int r = 0; r < 4; ++r){ mrow[rf][r] = -1e30f; lrow[rf][r] = 0.f; }
  }

  const int nt = 2*qb + 10;   // causal: tiles with any key <= qmax+512
  for (int t = 0; t < nt; ++t){
    __syncthreads();   // previous iter's LDS reads done before re-stage
    // --- stage K tile: f32 -> bf16, XOR-swizzled ds_write_b128 ---
    {
      int row = tid >> 2, q4 = tid & 3;      // 4 threads per 64-elem row
      const float4v* kp = (const float4v*)(presK + (((size_t)bh*NS_ + t*64 + row) << 6) + q4*16);
      union { float4v v[4]; float f[16]; } u;
      u.v[0] = kp[0]; u.v[1] = kp[1]; u.v[2] = kp[2]; u.v[3] = kp[3];
      bf16x8 p0, p1;
      #pragma unroll
      for (int j = 0; j < 8; ++j){
        p0[j] = (short)f2bf(u.f[j]);
        p1[j] = (short)f2bf(u.f[8 + j]);
      }
      int sw = (row & 7) << 4;
      char* kb = (char*)Klds + row*128;
      *(bf16x8*)(kb + ((q4*32) ^ sw))      = p0;
      *(bf16x8*)(kb + ((q4*32 + 16) ^ sw)) = p1;
    }
    // --- stage V tile transposed: pack kv-pairs into dwords ---
    {
      int kvp = tid & 31, d0 = (tid >> 5) * 8;   // kv = 2*kvp, 8 d-values
      const float* vp = presV + (((size_t)bh*NS_ + t*64 + 2*kvp) << 6) + d0;
      union { float4v v[2]; float f[8]; } a0, a1;
      a0.v[0] = ((const float4v*)vp)[0];        a0.v[1] = ((const float4v*)vp)[1];
      a1.v[0] = ((const float4v*)(vp + 64))[0]; a1.v[1] = ((const float4v*)(vp + 64))[1];
      #pragma unroll
      for (int j = 0; j < 8; ++j){
        unsigned pk = (unsigned)f2bf(a0.f[j]) | ((unsigned)f2bf(a1.f[j]) << 16);
        *(unsigned*)((char*)Vt + (size_t)(d0 + j)*144 + kvp*4) = pk;
      }
    }
    __syncthreads();

    // --- S = Q K^T ---
    f32x4 s[2][4];
    #pragma unroll
    for (int cf = 0; cf < 4; ++cf){
      int row = cf*16 + li;
      int sw = (row & 7) << 4;
      const char* kb = (const char*)Klds + row*128;
      bf16x8 bk0 = *(const bf16x8*)(kb + ((g*16) ^ sw));
      bf16x8 bk1 = *(const bf16x8*)(kb + ((64 + g*16) ^ sw));
      #pragma unroll
      for (int rf = 0; rf < 2; ++rf){
        f32x4 a0 = (f32x4){0.f,0.f,0.f,0.f};
        a0 = __builtin_amdgcn_mfma_f32_16x16x32_bf16(qf[rf][0], bk0, a0, 0, 0, 0);
        a0 = __builtin_amdgcn_mfma_f32_16x16x32_bf16(qf[rf][1], bk1, a0, 0, 0, 0);
        s[rf][cf] = a0;
      }
    }

    const int kbase = t*64;
    #pragma unroll
    for (int rf = 0; rf < 2; ++rf){
      float pm[4], al[4];
      #pragma unroll
      for (int r = 0; r < 4; ++r){
        int q = q0 + rf*16 + g*4 + r;
        int lim = q + 512 - kbase;          // key_local <= lim allowed
        float mx = -1e30f;
        #pragma unroll
        for (int cf = 0; cf < 4; ++cf){
          int kl = cf*16 + li;
          float v2 = s[rf][cf][r]*0.125f;
          v2 = (kl <= lim) ? v2 : -10000.0f;  // matches reference mask exactly
          s[rf][cf][r] = v2;
          mx = fmaxf(mx, v2);
        }
        pm[r] = mx;
      }
      #pragma unroll
      for (int r = 0; r < 4; ++r){
        #pragma unroll
        for (int d2 = 1; d2 < 16; d2 <<= 1)
          pm[r] = fmaxf(pm[r], __shfl_xor(pm[r], d2, 64));
        float mn = fmaxf(mrow[rf][r], pm[r]);
        al[r] = __expf(mrow[rf][r] - mn);
        mrow[rf][r] = mn;
      }
      float rs[4] = {0.f,0.f,0.f,0.f};
      #pragma unroll
      for (int cf = 0; cf < 4; ++cf){
        #pragma unroll
        for (int r = 0; r < 4; ++r){
          float p = __expf(s[rf][cf][r] - mrow[rf][r]);
          rs[r] += p;
          Plds[w][(rf*16 + g*4 + r)*72 + cf*16 + li] = f2bf(p);
        }
      }
      #pragma unroll
      for (int r = 0; r < 4; ++r){
        #pragma unroll
        for (int d2 = 1; d2 < 16; d2 <<= 1)
          rs[r] += __shfl_xor(rs[r], d2, 64);
        lrow[rf][r] = lrow[rf][r]*al[r] + rs[r];
      }
      #pragma unroll
      for (int df = 0; df < 4; ++df)
        #pragma unroll
        for (int r = 0; r < 4; ++r)
          o[rf][df][r] *= al[r];
    }

    // --- O += P V ---
    bf16x8 bv[4][2];
    #pragma unroll
    for (int df = 0; df < 4; ++df){
      bv[df][0] = *(const bf16x8*)(Vt + (df*16 + li)*72 + g*8);
      bv[df][1] = *(const bf16x8*)(Vt + (df*16 + li)*72 + 32 + g*8);
    }
    #pragma unroll
    for (int rf = 0; rf < 2; ++rf){
      bf16x8 pa0 = *(const bf16x8*)(Plds[w] + (rf*16 + li)*72 + g*8);
      bf16x8 pa1 = *(const bf16x8*)(Plds[w] + (rf*16 + li)*72 + 32 + g*8);
      #pragma unroll
      for (int df = 0; df < 4; ++df){
        o[rf][df] = __builtin_amdgcn_mfma_f32_16x16x32_bf16(pa0, bv[df][0], o[rf][df], 0, 0, 0);
        o[rf][df] = __builtin_amdgcn_mfma_f32_16x16x32_bf16(pa1, bv[df][1], o[rf][df], 0, 0, 0);
      }
    }
  }

  const int b = bh >> 4, h = bh & 15;
  #pragma unroll
  for (int rf = 0; rf < 2; ++rf){
    float inv[4];
    #pragma unroll
    for (int r = 0; r < 4; ++r) inv[r] = 1.0f / lrow[rf][r];
    #pragma unroll
    for (int df = 0; df < 4; ++df)
      #pragma unroll
      for (int r = 0; r < 4; ++r){
        int q = q0 + rf*16 + g*4 + r;
        Aout[((size_t)b*S_ + q)*NX_ + h*64 + df*16 + li] = f2bf(o[rf][df][r]*inv[r]);
      }
  }
}

// ---------------------------------------------------------------- launch

extern "C" void kernel_launch(void* const* d_in, const int* in_sizes, int n_in,
                              void* d_out, int out_size, void* d_ws, size_t ws_size,
                              hipStream_t stream){
  const float* x          = (const float*)d_in[0];
  const float* layer_past = (const float*)d_in[1];
  const float* c_attn_w   = (const float*)d_in[2];
  const float* c_attn_b   = (const float*)d_in[3];
  const float* c_proj_w   = (const float*)d_in[4];
  const float* c_proj_b   = (const float*)d_in[5];

  float* out = (float*)d_out;
  float* present = out + (size_t)B_*S_*NX_;   // a is [B,S,NX] = 8,388,608 f32
  float* presK = present;
  float* presV = present + BHND_;

  // workspace: 20,971,520 shorts = 41.9 MiB total
  unsigned short* ws = (unsigned short*)d_ws;
  unsigned short* xb     = ws;                              // 8,388,608 (reused as Ab after gemm<0>)
  unsigned short* wqkvT  = xb     + (size_t)8388608;        // 3,145,728  [3072][1024]
  unsigned short* wprojT = wqkvT  + (size_t)3145728;        // 1,048,576  [1024][1024]
  unsigned short* Qb     = wprojT + (size_t)1048576;        // 8,388,608  [B*H][2048][64]
  unsigned short* Ab     = xb;                              // alias: xb dead after gemm<0>

  cvt_f32_bf16<<<2048, 256, 0, stream>>>(x, xb, (int)(8388608/4));
  transpose_cvt<<<dim3(3072/32, 1024/32), 256, 0, stream>>>(c_attn_w, wqkvT, 1024, 3072);
  transpose_cvt<<<dim3(1024/32, 1024/32), 256, 0, stream>>>(c_proj_w, wprojT, 1024, 1024);
  past_kernel<<<2048, 256, 0, stream>>>(layer_past, present);

  gemm_bf16<0><<<dim3(64, 24), 256, 0, stream>>>(xb, wqkvT, c_attn_b, 1024, 3072,
                                                 nullptr, Qb, present);
  attn_kernel<<<dim3(16, 64), 256, 0, stream>>>(Qb, presK, presV, Ab);
  gemm_bf16<1><<<dim3(64, 8), 256, 0, stream>>>(Ab, wprojT, c_proj_b, 1024, 1024,
                                                out, nullptr, nullptr);
}

// Round 4
// 440.392 us; speedup vs baseline: 1.4164x; 1.4164x over previous
//
#include <hip/hip_runtime.h>

#define B_  4
#define S_  2048
#define NX_ 1024
#define H_  16
#define D_  64
#define P_  512
#define NS_ 2560   // P + S
#define BHND_ ((size_t)B_*H_*NS_*D_)   // 10,485,760

#define QSCALE_ 0.18033688011112042f   // 0.125 * log2(e)
#define MASKC_  -14426.950408889634f   // -10000 * log2(e)

typedef __attribute__((ext_vector_type(8))) short bf16x8;
typedef __attribute__((ext_vector_type(4))) float f32x4;
typedef __attribute__((ext_vector_type(4))) float float4v;
typedef __attribute__((ext_vector_type(4))) unsigned short ushort4v;

__device__ __forceinline__ unsigned short f2bf(float f){
  union { float f; unsigned u; } v; v.f = f;
  unsigned r = v.u + 0x7FFFu + ((v.u >> 16) & 1u);
  return (unsigned short)(r >> 16);
}

__device__ __forceinline__ void gll16(const void* g, void* l){
  __builtin_amdgcn_global_load_lds(
      (const __attribute__((address_space(1))) unsigned int*)g,
      (__attribute__((address_space(3))) unsigned int*)l, 16, 0, 0);
}

// barrier that drains LDS ops but leaves global (prefetch) loads in flight
__device__ __forceinline__ void bar_nodrain(){
  __builtin_amdgcn_sched_barrier(0);
  asm volatile("s_waitcnt lgkmcnt(0)" ::: "memory");
  __builtin_amdgcn_s_barrier();
  __builtin_amdgcn_sched_barrier(0);
}

// ---------------------------------------------------------------- prep kernels

__global__ void cvt_f32_bf16(const float* __restrict__ in, unsigned short* __restrict__ out, int n4){
  for (int i = blockIdx.x*blockDim.x + threadIdx.x; i < n4; i += gridDim.x*blockDim.x){
    float4v v = ((const float4v*)in)[i];
    ushort4v u = { f2bf(v.x), f2bf(v.y), f2bf(v.z), f2bf(v.w) };
    ((ushort4v*)out)[i] = u;
  }
}

// out[n][k] = bf16(in[k][n]); in: [K][N] f32
__global__ void transpose_cvt(const float* __restrict__ in, unsigned short* __restrict__ out, int K, int N){
  __shared__ float tile[32][33];
  int n0 = blockIdx.x*32, k0 = blockIdx.y*32;
  int tx = threadIdx.x & 31, ty = threadIdx.x >> 5;   // 256 thr = 32x8
  #pragma unroll
  for (int r = 0; r < 32; r += 8)
    tile[ty + r][tx] = in[(size_t)(k0 + ty + r)*N + n0 + tx];
  __syncthreads();
  #pragma unroll
  for (int r = 0; r < 32; r += 8)
    out[(size_t)(n0 + ty + r)*K + k0 + tx] = f2bf(tile[tx][ty + r]);
}

// layer_past [2][B][H][512][64] f32 -> present positions 0..511 (f32 passthrough, exact)
__global__ void past_kernel(const float* __restrict__ past, float* __restrict__ present){
  const int total4 = 2*B_*H_*P_*D_/4;  // 1,048,576 float4s
  for (int i = blockIdx.x*blockDim.x + threadIdx.x; i < total4; i += gridDim.x*blockDim.x){
    int d4  = i & 15;
    int pos = (i >> 4) & 511;
    int h   = (i >> 13) & 15;
    int b   = (i >> 17) & 3;
    int kv  = i >> 19;
    float4v v = ((const float4v*)past)[i];
    size_t off = (((size_t)(b*H_ + h))*NS_ + pos)*D_ + d4*4;
    ((float4v*)present)[((size_t)kv*BHND_ + off) >> 2] = v;
  }
}

// ---------------------------------------------------------------- GEMM (m97-style 128x128, BK=32)
// A [M][K] bf16 row-major, Bt [N][K] bf16 (pre-transposed weights), f32 accum.
// EPI 0: qkv epilogue (Q -> bf16 Qb pre-scaled by QSCALE_; K/V -> f32 present). EPI 1: f32 out + bias.
template<int EPI>
__global__ __launch_bounds__(256, 2) void gemm_bf16(
    const unsigned short* __restrict__ A,
    const unsigned short* __restrict__ Bt,
    const float* __restrict__ bias,
    const int K, const int N,
    float* __restrict__ out_f32,
    unsigned short* __restrict__ out_q,
    float* __restrict__ present)
{
  __shared__ unsigned short As[128*32];  // 8 KB, [m][k] linear, 64B rows
  __shared__ unsigned short Bs[128*32];
  const int bm = blockIdx.x, bn = blockIdx.y;
  const int tid = threadIdx.x, lane = tid & 63, w = tid >> 6;
  const int wr = w >> 1, wc = w & 1;
  const int g = lane >> 4, li = lane & 15;
  f32x4 acc[4][4] = {};
  const char* Ab = (const char*)A + (size_t)(bm*128)*(K*2);
  const char* Bb = (const char*)Bt + (size_t)(bn*128)*(K*2);

  for (int kt = 0; kt < K; kt += 32){
    #pragma unroll
    for (int c = 0; c < 2; ++c){
      int off = c*4096 + w*1024 + lane*16;  // linear byte offset in 8KB tile
      int row = off >> 6, col = off & 63;
      gll16(Ab + (size_t)row*(K*2) + (size_t)kt*2 + col, (char*)As + c*4096 + w*1024);
      gll16(Bb + (size_t)row*(K*2) + (size_t)kt*2 + col, (char*)Bs + c*4096 + w*1024);
    }
    __syncthreads();
    bf16x8 af[4], bfr[4];
    #pragma unroll
    for (int mf = 0; mf < 4; ++mf)
      af[mf] = *(const bf16x8*)((const char*)As + (wr*64 + mf*16 + li)*64 + g*16);
    #pragma unroll
    for (int nf = 0; nf < 4; ++nf)
      bfr[nf] = *(const bf16x8*)((const char*)Bs + (wc*64 + nf*16 + li)*64 + g*16);
    #pragma unroll
    for (int mf = 0; mf < 4; ++mf)
      #pragma unroll
      for (int nf = 0; nf < 4; ++nf)
        acc[mf][nf] = __builtin_amdgcn_mfma_f32_16x16x32_bf16(af[mf], bfr[nf], acc[mf][nf], 0, 0, 0);
    __syncthreads();
  }

  #pragma unroll
  for (int mf = 0; mf < 4; ++mf){
    #pragma unroll
    for (int nf = 0; nf < 4; ++nf){
      int n = bn*128 + wc*64 + nf*16 + li;
      float bsv = bias[n];
      #pragma unroll
      for (int r = 0; r < 4; ++r){
        int m = bm*128 + wr*64 + mf*16 + g*4 + r;
        float v = acc[mf][nf][r] + bsv;
        if (EPI == 0){
          int b = m >> 11, sI = m & 2047;
          if (n < 1024){
            int hh = n >> 6, d = n & 63;
            out_q[(((size_t)(b*H_ + hh)*S_ + sI) << 6) + d] = f2bf(v * QSCALE_);
          } else {
            int cc = n & 1023; int hh = cc >> 6, d = cc & 63;
            size_t off = (((size_t)(b*H_ + hh)*NS_ + P_ + sI) << 6) + d;
            present[(n < 2048 ? (size_t)0 : BHND_) + off] = v;
          }
        } else {
          out_f32[(size_t)m*N + n] = v;
        }
      }
    }
  }
}

// ---------------------------------------------------------------- flash attention
// grid (4, 64); 512 threads = 8 waves x 32 q-rows = 256-row supertile.
// Block processes supertile blockIdx.x then supertile 7-blockIdx.x -> 52 tiles each (balanced).
// K/V f32 from present, reg-prefetched one tile ahead; nodrain barriers keep loads in flight.
__global__ __launch_bounds__(512, 2) void attn_kernel(
    const unsigned short* __restrict__ Qb,   // [B*H][2048][64] bf16, pre-scaled by QSCALE_
    const float* __restrict__ presK,         // [B*H][2560][64] f32
    const float* __restrict__ presV,         // [B*H][2560][64] f32
    unsigned short* __restrict__ Aout)       // [B][2048][1024] bf16
{
  __shared__ unsigned short Klds[64*64];     // 8 KB, XOR-swizzled rows (128B)
  __shared__ unsigned short Vt[64*72];       // [d][kv], row stride 144B
  __shared__ unsigned short Plds[8][32*72];  // per-wave P tile [q][kv]

  const int bh = blockIdx.y;
  const int tid = threadIdx.x, lane = tid & 63, w = tid >> 6;
  const int g = lane >> 4, li = lane & 15;

  // staging coords (512 threads)
  const int krow = tid >> 3, kq8 = tid & 7;          // K: row, 8-float chunk
  const int vkvp = tid & 31, vd0 = (tid >> 5) << 2;  // V: kv-pair, 4 d-values

  const float* Kbase = presK + (((size_t)bh*NS_) << 6);
  const float* Vbase = presV + (((size_t)bh*NS_) << 6);
  const int b = bh >> 4, h = bh & 15;

  #pragma unroll 1
  for (int seg = 0; seg < 2; ++seg){
    const int qsup = seg ? (7 - blockIdx.x) : blockIdx.x;
    const int nt = 4*qsup + 12;
    const int q0w = qsup*256 + w*32;

    // Q fragments: rows q0w+rf*16+li, k-slices of 8
    bf16x8 qf[2][2];
    #pragma unroll
    for (int rf = 0; rf < 2; ++rf)
      #pragma unroll
      for (int ks = 0; ks < 2; ++ks)
        qf[rf][ks] = *(const bf16x8*)(Qb + (((size_t)bh*S_ + q0w + rf*16 + li) << 6) + ks*32 + g*8);

    f32x4 o[2][4];
    float mrow[2][4], lrow[2][4];
    #pragma unroll
    for (int rf = 0; rf < 2; ++rf){
      #pragma unroll
      for (int df = 0; df < 4; ++df) o[rf][df] = (f32x4){0.f,0.f,0.f,0.f};
      #pragma unroll
      for (int r = 0; r < 4; ++r){ mrow[rf][r] = -1e30f; lrow[rf][r] = 0.f; }
    }

    // prologue: load tile 0 into regs
    float4v ka, kb2, va, vb;
    {
      const float* kp = Kbase + ((size_t)krow << 6) + kq8*8;
      ka = ((const float4v*)kp)[0]; kb2 = ((const float4v*)kp)[1];
      const float* vp = Vbase + ((size_t)(2*vkvp) << 6) + vd0;
      va = *(const float4v*)vp; vb = *(const float4v*)(vp + 64);
    }

    #pragma unroll 1
    for (int t = 0; t < nt; ++t){
      bar_nodrain();   // prev tile's LDS reads done; prefetch loads still in flight
      // --- stage K (f32->bf16, XOR-swizzled b128 write) ---
      {
        bf16x8 kw;
        #pragma unroll
        for (int j = 0; j < 4; ++j){ kw[j] = (short)f2bf(ka[j]); kw[4+j] = (short)f2bf(kb2[j]); }
        *(bf16x8*)((char*)Klds + krow*128 + ((kq8*16) ^ ((krow & 7) << 4))) = kw;
      }
      // --- stage V transposed (pack kv-pairs into dwords) ---
      {
        #pragma unroll
        for (int j = 0; j < 4; ++j){
          unsigned pk = (unsigned)f2bf(va[j]) | ((unsigned)f2bf(vb[j]) << 16);
          *(unsigned*)((char*)Vt + (size_t)(vd0 + j)*144 + vkvp*4) = pk;
        }
      }
      // --- prefetch tile t+1 ---
      if (t + 1 < nt){
        const float* kp = Kbase + ((size_t)((t+1)*64 + krow) << 6) + kq8*8;
        ka = ((const float4v*)kp)[0]; kb2 = ((const float4v*)kp)[1];
        const float* vp = Vbase + ((size_t)((t+1)*64 + 2*vkvp) << 6) + vd0;
        va = *(const float4v*)vp; vb = *(const float4v*)(vp + 64);
      }
      bar_nodrain();   // staged LDS visible; prefetch stays in flight

      const int kbase = t*64;
      if (kbase <= q0w + 543){                      // wave has any unmasked key in this tile
        const bool needmask = (kbase + 63) > (q0w + 512);

        // --- S = Q K^T (log2-scaled since Q pre-scaled) ---
        f32x4 s[2][4];
        #pragma unroll
        for (int cf = 0; cf < 4; ++cf){
          int row = cf*16 + li;
          int sw = (row & 7) << 4;
          const char* kb = (const char*)Klds + row*128;
          bf16x8 bk0 = *(const bf16x8*)(kb + ((g*16) ^ sw));
          bf16x8 bk1 = *(const bf16x8*)(kb + ((64 + g*16) ^ sw));
          #pragma unroll
          for (int rf = 0; rf < 2; ++rf){
            f32x4 a0 = (f32x4){0.f,0.f,0.f,0.f};
            a0 = __builtin_amdgcn_mfma_f32_16x16x32_bf16(qf[rf][0], bk0, a0, 0, 0, 0);
            a0 = __builtin_amdgcn_mfma_f32_16x16x32_bf16(qf[rf][1], bk1, a0, 0, 0, 0);
            s[rf][cf] = a0;
          }
        }

        #pragma unroll
        for (int rf = 0; rf < 2; ++rf){
          float pm[4], al[4];
          #pragma unroll
          for (int r = 0; r < 4; ++r){
            if (needmask){
              int q = q0w + rf*16 + g*4 + r;
              int lim = q + 512 - kbase;            // key_local <= lim allowed
              #pragma unroll
              for (int cf = 0; cf < 4; ++cf){
                int kl = cf*16 + li;
                s[rf][cf][r] = (kl <= lim) ? s[rf][cf][r] : MASKC_;
              }
            }
            float mx = fmaxf(fmaxf(s[rf][0][r], s[rf][1][r]), fmaxf(s[rf][2][r], s[rf][3][r]));
            pm[r] = mx;
          }
          #pragma unroll
          for (int r = 0; r < 4; ++r){
            #pragma unroll
            for (int d2 = 1; d2 < 16; d2 <<= 1)
              pm[r] = fmaxf(pm[r], __shfl_xor(pm[r], d2, 64));
            float mn = fmaxf(mrow[rf][r], pm[r]);
            al[r] = __builtin_amdgcn_exp2f(mrow[rf][r] - mn);
            mrow[rf][r] = mn;
          }
          float rs[4] = {0.f,0.f,0.f,0.f};
          #pragma unroll
          for (int cf = 0; cf < 4; ++cf){
            #pragma unroll
            for (int r = 0; r < 4; ++r){
              float p = __builtin_amdgcn_exp2f(s[rf][cf][r] - mrow[rf][r]);
              rs[r] += p;
              Plds[w][(rf*16 + g*4 + r)*72 + cf*16 + li] = f2bf(p);
            }
          }
          #pragma unroll
          for (int r = 0; r < 4; ++r){
            #pragma unroll
            for (int d2 = 1; d2 < 16; d2 <<= 1)
              rs[r] += __shfl_xor(rs[r], d2, 64);
            lrow[rf][r] = lrow[rf][r]*al[r] + rs[r];
          }
          #pragma unroll
          for (int df = 0; df < 4; ++df)
            #pragma unroll
            for (int r = 0; r < 4; ++r)
              o[rf][df][r] *= al[r];
        }

        // --- O += P V ---
        bf16x8 bv[4][2];
        #pragma unroll
        for (int df = 0; df < 4; ++df){
          bv[df][0] = *(const bf16x8*)(Vt + (df*16 + li)*72 + g*8);
          bv[df][1] = *(const bf16x8*)(Vt + (df*16 + li)*72 + 32 + g*8);
        }
        #pragma unroll
        for (int rf = 0; rf < 2; ++rf){
          bf16x8 pa0 = *(const bf16x8*)(Plds[w] + (rf*16 + li)*72 + g*8);
          bf16x8 pa1 = *(const bf16x8*)(Plds[w] + (rf*16 + li)*72 + 32 + g*8);
          #pragma unroll
          for (int df = 0; df < 4; ++df){
            o[rf][df] = __builtin_amdgcn_mfma_f32_16x16x32_bf16(pa0, bv[df][0], o[rf][df], 0, 0, 0);
            o[rf][df] = __builtin_amdgcn_mfma_f32_16x16x32_bf16(pa1, bv[df][1], o[rf][df], 0, 0, 0);
          }
        }
      }
    }

    // --- segment epilogue ---
    #pragma unroll
    for (int rf = 0; rf < 2; ++rf){
      float inv[4];
      #pragma unroll
      for (int r = 0; r < 4; ++r) inv[r] = 1.0f / lrow[rf][r];
      #pragma unroll
      for (int df = 0; df < 4; ++df)
        #pragma unroll
        for (int r = 0; r < 4; ++r){
          int q = q0w + rf*16 + g*4 + r;
          Aout[((size_t)b*S_ + q)*NX_ + h*64 + df*16 + li] = f2bf(o[rf][df][r]*inv[r]);
        }
    }
  }
}

// ---------------------------------------------------------------- launch

extern "C" void kernel_launch(void* const* d_in, const int* in_sizes, int n_in,
                              void* d_out, int out_size, void* d_ws, size_t ws_size,
                              hipStream_t stream){
  const float* x          = (const float*)d_in[0];
  const float* layer_past = (const float*)d_in[1];
  const float* c_attn_w   = (const float*)d_in[2];
  const float* c_attn_b   = (const float*)d_in[3];
  const float* c_proj_w   = (const float*)d_in[4];
  const float* c_proj_b   = (const float*)d_in[5];

  float* out = (float*)d_out;
  float* present = out + (size_t)B_*S_*NX_;   // a is [B,S,NX] = 8,388,608 f32
  float* presK = present;
  float* presV = present + BHND_;

  // workspace: 20,971,520 shorts = 41.9 MiB total
  unsigned short* ws = (unsigned short*)d_ws;
  unsigned short* xb     = ws;                              // 8,388,608 (reused as Ab after gemm<0>)
  unsigned short* wqkvT  = xb     + (size_t)8388608;        // 3,145,728  [3072][1024]
  unsigned short* wprojT = wqkvT  + (size_t)3145728;        // 1,048,576  [1024][1024]
  unsigned short* Qb     = wprojT + (size_t)1048576;        // 8,388,608  [B*H][2048][64]
  unsigned short* Ab     = xb;                              // alias: xb dead after gemm<0>

  cvt_f32_bf16<<<2048, 256, 0, stream>>>(x, xb, (int)(8388608/4));
  transpose_cvt<<<dim3(3072/32, 1024/32), 256, 0, stream>>>(c_attn_w, wqkvT, 1024, 3072);
  transpose_cvt<<<dim3(1024/32, 1024/32), 256, 0, stream>>>(c_proj_w, wprojT, 1024, 1024);
  past_kernel<<<2048, 256, 0, stream>>>(layer_past, present);

  gemm_bf16<0><<<dim3(64, 24), 256, 0, stream>>>(xb, wqkvT, c_attn_b, 1024, 3072,
                                                 nullptr, Qb, present);
  attn_kernel<<<dim3(4, 64), 512, 0, stream>>>(Qb, presK, presV, Ab);
  gemm_bf16<1><<<dim3(64, 8), 256, 0, stream>>>(Ab, wprojT, c_proj_b, 1024, 1024,
                                                out, nullptr, nullptr);
}